// Round 1
// baseline (54127.295 us; speedup 1.0000x reference)
//
#include <hip/hip_runtime.h>
#include <hip/hip_bf16.h>
#include <stdint.h>

// ---------------------------------------------------------------------------
// Bidirectional 5-layer LSTM (all-sigmoid), B=16, T=1024, D=1024, U=512.
// Strategy:
//   - per layer: transpose W,Uh -> [N][K] bf16; big MFMA GEMM xz = y@W + b;
//     persistent recurrence kernel (16 wg/dir, Uh slice resident in LDS,
//     h broadcast via agent-scope atomics + per-step arrival counters).
// Workspace: ~204 MB (yA 32MB, yB 32MB, xz 128MB, Wt 8MB, Ut 4MB, flags 40KB).
// ---------------------------------------------------------------------------

typedef __attribute__((ext_vector_type(8))) short short8;
typedef __attribute__((ext_vector_type(4))) float f32x4;

union U128 { uint4 u; short8 s; };
static __device__ __forceinline__ short8 as_short8(uint4 v) { U128 x; x.u = v; return x.s; }

static __device__ __forceinline__ float sigf(float x) { return 1.0f / (1.0f + __expf(-x)); }

static __device__ __forceinline__ uint32_t f2bfbits(float f) {
  union { float f; uint32_t u; } x; x.f = f;
  return (x.u + 0x7fffu + ((x.u >> 16) & 1u)) >> 16;   // RNE; h in (0,1), no NaN
}

// ---------------- x (fp32) -> bf16 ----------------
__global__ __launch_bounds__(256) void f32_to_bf16_k(const float* __restrict__ in,
                                                     __hip_bfloat16* __restrict__ out,
                                                     int n4) {
  int i = blockIdx.x * 256 + threadIdx.x;
  if (i < n4) {
    float4 v = ((const float4*)in)[i];
    uint32_t lo = f2bfbits(v.x) | (f2bfbits(v.y) << 16);
    uint32_t hi = f2bfbits(v.z) | (f2bfbits(v.w) << 16);
    ((uint2*)out)[i] = make_uint2(lo, hi);
  }
}

// ---------------- [2][R][2048] fp32 -> [2][2048][R] bf16 transpose ----------------
__global__ __launch_bounds__(256) void transpose_bf16_k(const float* __restrict__ in,
                                                        __hip_bfloat16* __restrict__ outp,
                                                        int R) {
  __shared__ float tile[64][65];
  int d = blockIdx.z;
  int k0 = blockIdx.x * 64;
  int c0 = blockIdx.y * 64;
  const float* inb = in + (size_t)d * R * 2048;
  __hip_bfloat16* ob = outp + (size_t)d * 2048 * R;
  int col = threadIdx.x & 63, rr = threadIdx.x >> 6;
#pragma unroll
  for (int i = 0; i < 16; ++i) {
    int r = rr + i * 4;
    tile[r][col] = inb[(size_t)(k0 + r) * 2048 + c0 + col];
  }
  __syncthreads();
#pragma unroll
  for (int i = 0; i < 16; ++i) {
    int r = rr + i * 4;
    ob[(size_t)(c0 + r) * R + k0 + col] = __float2bfloat16(tile[col][r]);
  }
}

// ---------------- xz GEMM: [16384,1024] @ [2][2048,1024]^T -> [2][16384][2048] bf16 -----
// 128x128 tile, BK=64, pre-fragmented LDS (conflict-free ds_read_b128), 4 waves (2x2).
__global__ __launch_bounds__(256) void gemm_xz_k(const __hip_bfloat16* __restrict__ y,
                                                 const __hip_bfloat16* __restrict__ Wt,
                                                 const float* __restrict__ bias,
                                                 __hip_bfloat16* __restrict__ xz) {
  __shared__ uint4 Asl[8 * 2 * 64];  // [mtile][kc][lane] : A[m=lane&15][k=kc*32+(lane>>4)*8+j]
  __shared__ uint4 Bsl[8 * 2 * 64];
  int m0 = blockIdx.x * 128;
  int dir = blockIdx.y >> 4;
  int n0 = (blockIdx.y & 15) * 128;
  int tid = threadIdx.x, lane = tid & 63, wv = tid >> 6;
  int wm = wv & 1, wn = wv >> 1;
  const __hip_bfloat16* Wd = Wt + (size_t)dir * 2048 * 1024;
  f32x4 acc[4][4] = {};
  for (int kb = 0; kb < 1024; kb += 64) {
    __syncthreads();
#pragma unroll
    for (int i = 0; i < 4; ++i) {
      int slot = i * 256 + tid;
      int ln = slot & 63, kc = (slot >> 6) & 1, mt = slot >> 7;
      int row = mt * 16 + (ln & 15);
      int kk = kc * 32 + (ln >> 4) * 8;
      Asl[slot] = *(const uint4*)(y + (size_t)(m0 + row) * 1024 + kb + kk);
      Bsl[slot] = *(const uint4*)(Wd + (size_t)(n0 + row) * 1024 + kb + kk);
    }
    __syncthreads();
#pragma unroll
    for (int kc = 0; kc < 2; ++kc) {
      short8 af[4], bf[4];
#pragma unroll
      for (int i = 0; i < 4; ++i) {
        af[i] = as_short8(Asl[((wm * 4 + i) * 2 + kc) * 64 + lane]);
        bf[i] = as_short8(Bsl[((wn * 4 + i) * 2 + kc) * 64 + lane]);
      }
#pragma unroll
      for (int i = 0; i < 4; ++i)
#pragma unroll
        for (int j = 0; j < 4; ++j)
          acc[i][j] = __builtin_amdgcn_mfma_f32_16x16x32_bf16(af[i], bf[j], acc[i][j], 0, 0, 0);
    }
  }
  // epilogue: C/D layout col=lane&15, row=(lane>>4)*4+r  [m89-verified]
  int cq = lane >> 4, cn = lane & 15;
#pragma unroll
  for (int i = 0; i < 4; ++i)
#pragma unroll
    for (int j = 0; j < 4; ++j) {
      int n_g = n0 + (wn * 4 + j) * 16 + cn;
      float bv = bias[dir * 2048 + n_g];
#pragma unroll
      for (int r = 0; r < 4; ++r) {
        int m = m0 + (wm * 4 + i) * 16 + cq * 4 + r;
        xz[((size_t)dir * 16384 + m) * 2048 + n_g] = __float2bfloat16(acc[i][j][r] + bv);
      }
    }
}

// ---------------- persistent bidirectional recurrence ----------------
// 32 blocks: dir = blockIdx&1, slice = blockIdx>>1 (16 slices/dir, 32 u-cols each).
// LDS: Uh slice pre-fragmented 128KB + z exchange 8KB = 136KB (dynamic).
__global__ __launch_bounds__(256) void lstm_rec_k(const __hip_bfloat16* __restrict__ Ut,  // [2][2048][512]
                                                  const __hip_bfloat16* __restrict__ xz,  // [2][16384][2048]
                                                  __hip_bfloat16* __restrict__ ynext,     // [16][1024][1024]
                                                  float* __restrict__ outf,               // last layer or null
                                                  int* __restrict__ arrive) {             // [2][1024] zeroed
  extern __shared__ char smem[];
  uint4* uh = (uint4*)smem;                      // 8192 slots x 16B
  float* zbuf = (float*)(smem + 131072);         // [16][128]
  int dir = blockIdx.x & 1;
  int swg = blockIdx.x >> 1;
  int u0 = swg * 32;
  int tid = threadIdx.x, lane = tid & 63, wv = tid >> 6;
  int quad = lane >> 4, l15 = lane & 15;
  const __hip_bfloat16* Ud = Ut + (size_t)dir * 2048 * 512;

  // fill LDS with Uh slice, pre-fragmented: slot=((nt*16)+kc)*64+lane ->
  // B[k=kc*32+(lane>>4)*8+j][n = (nt>>1)*512 + u0 + (nt&1)*16 + (lane&15)]
#pragma unroll 4
  for (int i = 0; i < 32; ++i) {
    int slot = i * 256 + tid;
    int ls = slot & 63, kc = (slot >> 6) & 15, nt = slot >> 10;
    int n_g = (nt >> 1) * 512 + u0 + (nt & 1) * 16 + (ls & 15);
    int k = kc * 32 + (ls >> 4) * 8;
    uh[slot] = *(const uint4*)(Ud + (size_t)n_g * 512 + k);
  }
  __syncthreads();

  int nt0 = wv * 2, nt1 = wv * 2 + 1;
  int ng0 = (nt0 >> 1) * 512 + u0 + (nt0 & 1) * 16 + l15;
  int ng1 = (nt1 >> 1) * 512 + u0 + (nt1 & 1) * 16 + l15;
  int p = tid * 2, pb = p >> 5, pj = p & 31;   // this thread's (batch, u-offset) pair
  float c0 = 0.f, c1 = 0.f;
  int* flag = arrive + dir * 1024;

  for (int s = 0; s < 1024; ++s) {
    int t = dir ? (1023 - s) : s;
    f32x4 z0 = {}, z1 = {};
    if (s > 0) {
      int tprev = dir ? (t + 1) : (t - 1);
      if (tid == 0) {
        while (__hip_atomic_load(flag + (s - 1), __ATOMIC_ACQUIRE, __HIP_MEMORY_SCOPE_AGENT) < 16) { }
      }
      __syncthreads();
      // A fragments: lane batch = l15, k-octet by quad; agent-scope (uncached) loads
      const __hip_bfloat16* hrow = ynext + ((size_t)(l15 * 1024 + tprev) * 1024 + dir * 512);
      uint4 a[16];
#pragma unroll
      for (int kc = 0; kc < 16; ++kc) {
        uint32_t* sp = (uint32_t*)(hrow + kc * 32 + quad * 8);
        uint4 v;
        v.x = __hip_atomic_load(sp + 0, __ATOMIC_RELAXED, __HIP_MEMORY_SCOPE_AGENT);
        v.y = __hip_atomic_load(sp + 1, __ATOMIC_RELAXED, __HIP_MEMORY_SCOPE_AGENT);
        v.z = __hip_atomic_load(sp + 2, __ATOMIC_RELAXED, __HIP_MEMORY_SCOPE_AGENT);
        v.w = __hip_atomic_load(sp + 3, __ATOMIC_RELAXED, __HIP_MEMORY_SCOPE_AGENT);
        a[kc] = v;
      }
#pragma unroll
      for (int kc = 0; kc < 16; ++kc) {
        short8 afrag = as_short8(a[kc]);
        z0 = __builtin_amdgcn_mfma_f32_16x16x32_bf16(afrag, as_short8(uh[(nt0 * 16 + kc) * 64 + lane]), z0, 0, 0, 0);
        z1 = __builtin_amdgcn_mfma_f32_16x16x32_bf16(afrag, as_short8(uh[(nt1 * 16 + kc) * 64 + lane]), z1, 0, 0, 0);
      }
    }
    // add xz and publish to zbuf ([16][g*32+j] layout; local col nt*16+l15 == g*32+j)
#pragma unroll
    for (int r = 0; r < 4; ++r) {
      int m = quad * 4 + r;
      float x0 = __bfloat162float(xz[((size_t)dir * 16384 + m * 1024 + t) * 2048 + ng0]);
      float x1 = __bfloat162float(xz[((size_t)dir * 16384 + m * 1024 + t) * 2048 + ng1]);
      zbuf[m * 128 + nt0 * 16 + l15] = z0[r] + x0;
      zbuf[m * 128 + nt1 * 16 + l15] = z1[r] + x1;
    }
    __syncthreads();
    // gates: i,f,g,o = sigmoid; c = f*c + i*g; h = o*sigmoid(c)
    const float* zb = zbuf + pb * 128;
    float i0 = sigf(zb[pj]),     i1 = sigf(zb[pj + 1]);
    float f0 = sigf(zb[32 + pj]), f1 = sigf(zb[32 + pj + 1]);
    float g0 = sigf(zb[64 + pj]), g1 = sigf(zb[64 + pj + 1]);
    float o0 = sigf(zb[96 + pj]), o1 = sigf(zb[96 + pj + 1]);
    c0 = f0 * c0 + i0 * g0;
    c1 = f1 * c1 + i1 * g1;
    float h0 = o0 * sigf(c0);
    float h1 = o1 * sigf(c1);
    size_t oidx = (size_t)(pb * 1024 + t) * 1024 + dir * 512 + u0 + pj;
    uint32_t hp = f2bfbits(h0) | (f2bfbits(h1) << 16);
    __hip_atomic_store((uint32_t*)(ynext + oidx), hp, __ATOMIC_RELAXED, __HIP_MEMORY_SCOPE_AGENT);
    if (outf) { outf[oidx] = h0; outf[oidx + 1] = h1; }
    __syncthreads();   // zbuf reuse + drain h stores (barrier waits vmcnt(0))
    if (tid == 0)
      __hip_atomic_fetch_add(flag + s, 1, __ATOMIC_RELEASE, __HIP_MEMORY_SCOPE_AGENT);
  }
}

// ---------------------------------------------------------------------------
extern "C" void kernel_launch(void* const* d_in, const int* in_sizes, int n_in,
                              void* d_out, int out_size, void* d_ws, size_t ws_size,
                              hipStream_t stream) {
  const float* x  = (const float*)d_in[0];   // [16][1024][1024]
  const float* W  = (const float*)d_in[1];   // [5][2][1024][2048]
  const float* Uh = (const float*)d_in[2];   // [5][2][512][2048]
  const float* b  = (const float*)d_in[3];   // [5][2][2048]

  char* ws = (char*)d_ws;
  size_t off = 0;
  __hip_bfloat16* yA = (__hip_bfloat16*)(ws + off); off += (size_t)16 * 1024 * 1024 * 2;
  __hip_bfloat16* yB = (__hip_bfloat16*)(ws + off); off += (size_t)16 * 1024 * 1024 * 2;
  __hip_bfloat16* xz = (__hip_bfloat16*)(ws + off); off += (size_t)2 * 16 * 1024 * 2048 * 2;
  __hip_bfloat16* Wt = (__hip_bfloat16*)(ws + off); off += (size_t)2 * 2048 * 1024 * 2;
  __hip_bfloat16* Ut = (__hip_bfloat16*)(ws + off); off += (size_t)2 * 2048 * 512 * 2;
  int* flags = (int*)(ws + off); off += (size_t)5 * 2 * 1024 * 4;

  hipMemsetAsync(flags, 0, 5 * 2 * 1024 * sizeof(int), stream);
  f32_to_bf16_k<<<dim3(16384), dim3(256), 0, stream>>>(x, yA, 4194304);
  hipFuncSetAttribute(reinterpret_cast<const void*>(lstm_rec_k),
                      hipFuncAttributeMaxDynamicSharedMemorySize, 139264);
  for (int l = 0; l < 5; ++l) {
    transpose_bf16_k<<<dim3(16, 32, 2), dim3(256), 0, stream>>>(W + (size_t)l * 2 * 1024 * 2048, Wt, 1024);
    transpose_bf16_k<<<dim3(8, 32, 2),  dim3(256), 0, stream>>>(Uh + (size_t)l * 2 * 512 * 2048, Ut, 512);
    __hip_bfloat16* ycur = (l & 1) ? yB : yA;
    __hip_bfloat16* ynxt = (l & 1) ? yA : yB;
    gemm_xz_k<<<dim3(128, 32), dim3(256), 0, stream>>>(ycur, Wt, b + (size_t)l * 2 * 2048, xz);
    lstm_rec_k<<<dim3(32), dim3(256), 139264, stream>>>(
        Ut, xz, ynxt, (l == 4) ? (float*)d_out : nullptr, flags + l * 2048);
  }
}

// Round 2
// 21750.105 us; speedup vs baseline: 2.4886x; 2.4886x over previous
//
#include <hip/hip_runtime.h>
#include <hip/hip_bf16.h>
#include <stdint.h>

// ---------------------------------------------------------------------------
// Bidirectional 5-layer LSTM (all-sigmoid), B=16, T=1024, D=1024, U=512.
// R2: recurrence latency attack.
//   - h exchange: coalesced 8B agent-scope loads -> LDS (was 4096 scattered 4B
//     loads/step/block, 4x wave-redundant), MFMA A-frags via ds_read_b128.
//   - xz: GEMM writes per-(dir,slice,t) contiguous 4KB chunks; rec kernel does
//     one coalesced dwordx4/thread/step, prefetched one step ahead.
//   - flags: per-block slot on its own cache line (release store), 16 parallel
//     relaxed polls (was 16 serialized fetch_adds on one line).
// ---------------------------------------------------------------------------

typedef __attribute__((ext_vector_type(8))) short short8;
typedef __attribute__((ext_vector_type(4))) float f32x4;

union U128 { uint4 u; short8 s; };
static __device__ __forceinline__ short8 as_short8(uint4 v) { U128 x; x.u = v; return x.s; }

static __device__ __forceinline__ float sigf(float x) { return 1.0f / (1.0f + __expf(-x)); }

static __device__ __forceinline__ uint32_t f2bfbits(float f) {
  union { float f; uint32_t u; } x; x.f = f;
  return (x.u + 0x7fffu + ((x.u >> 16) & 1u)) >> 16;   // RNE; h in (0,1), no NaN
}
static __device__ __forceinline__ float bflo(uint32_t v) {
  union { uint32_t u; float f; } x; x.u = v << 16; return x.f;
}
static __device__ __forceinline__ float bfhi(uint32_t v) {
  union { uint32_t u; float f; } x; x.u = v & 0xffff0000u; return x.f;
}

// ---------------- x (fp32) -> bf16 ----------------
__global__ __launch_bounds__(256) void f32_to_bf16_k(const float* __restrict__ in,
                                                     __hip_bfloat16* __restrict__ out,
                                                     int n4) {
  int i = blockIdx.x * 256 + threadIdx.x;
  if (i < n4) {
    float4 v = ((const float4*)in)[i];
    uint32_t lo = f2bfbits(v.x) | (f2bfbits(v.y) << 16);
    uint32_t hi = f2bfbits(v.z) | (f2bfbits(v.w) << 16);
    ((uint2*)out)[i] = make_uint2(lo, hi);
  }
}

// ---------------- [2][R][2048] fp32 -> [2][2048][R] bf16 transpose ----------------
__global__ __launch_bounds__(256) void transpose_bf16_k(const float* __restrict__ in,
                                                        __hip_bfloat16* __restrict__ outp,
                                                        int R) {
  __shared__ float tile[64][65];
  int d = blockIdx.z;
  int k0 = blockIdx.x * 64;
  int c0 = blockIdx.y * 64;
  const float* inb = in + (size_t)d * R * 2048;
  __hip_bfloat16* ob = outp + (size_t)d * 2048 * R;
  int col = threadIdx.x & 63, rr = threadIdx.x >> 6;
#pragma unroll
  for (int i = 0; i < 16; ++i) {
    int r = rr + i * 4;
    tile[r][col] = inb[(size_t)(k0 + r) * 2048 + c0 + col];
  }
  __syncthreads();
#pragma unroll
  for (int i = 0; i < 16; ++i) {
    int r = rr + i * 4;
    ob[(size_t)(c0 + r) * R + k0 + col] = __float2bfloat16(tile[col][r]);
  }
}

// ---------------- xz GEMM: y[16384,1024] @ Wt[2][2048,1024]^T + b ----------------
// Output layout: xz[dir][swg(16)][t(1024)][q(4)][b(16)][j(32)]  (4KB per (dir,swg,t))
__global__ __launch_bounds__(256) void gemm_xz_k(const __hip_bfloat16* __restrict__ y,
                                                 const __hip_bfloat16* __restrict__ Wt,
                                                 const float* __restrict__ bias,
                                                 __hip_bfloat16* __restrict__ xz) {
  __shared__ uint4 Asl[8 * 2 * 64];
  __shared__ uint4 Bsl[8 * 2 * 64];
  int m0 = blockIdx.x * 128;
  int dir = blockIdx.y >> 4;
  int n0 = (blockIdx.y & 15) * 128;
  int tid = threadIdx.x, lane = tid & 63, wv = tid >> 6;
  int wm = wv & 1, wn = wv >> 1;
  const __hip_bfloat16* Wd = Wt + (size_t)dir * 2048 * 1024;
  f32x4 acc[4][4] = {};
  for (int kb = 0; kb < 1024; kb += 64) {
    __syncthreads();
#pragma unroll
    for (int i = 0; i < 4; ++i) {
      int slot = i * 256 + tid;
      int ln = slot & 63, kc = (slot >> 6) & 1, mt = slot >> 7;
      int row = mt * 16 + (ln & 15);
      int kk = kc * 32 + (ln >> 4) * 8;
      Asl[slot] = *(const uint4*)(y + (size_t)(m0 + row) * 1024 + kb + kk);
      Bsl[slot] = *(const uint4*)(Wd + (size_t)(n0 + row) * 1024 + kb + kk);
    }
    __syncthreads();
#pragma unroll
    for (int kc = 0; kc < 2; ++kc) {
      short8 af[4], bf[4];
#pragma unroll
      for (int i = 0; i < 4; ++i) {
        af[i] = as_short8(Asl[((wm * 4 + i) * 2 + kc) * 64 + lane]);
        bf[i] = as_short8(Bsl[((wn * 4 + i) * 2 + kc) * 64 + lane]);
      }
#pragma unroll
      for (int i = 0; i < 4; ++i)
#pragma unroll
        for (int j = 0; j < 4; ++j)
          acc[i][j] = __builtin_amdgcn_mfma_f32_16x16x32_bf16(af[i], bf[j], acc[i][j], 0, 0, 0);
    }
  }
  // epilogue: C/D layout col=lane&15, row=(lane>>4)*4+r  [m89-verified]
  int cq = lane >> 4, cn = lane & 15;
#pragma unroll
  for (int i = 0; i < 4; ++i)
#pragma unroll
    for (int j = 0; j < 4; ++j) {
      int n_g = n0 + (wn * 4 + j) * 16 + cn;
      int q = n_g >> 9, u = n_g & 511, swg = u >> 5, jj = u & 31;
      float bv = bias[dir * 2048 + n_g];
#pragma unroll
      for (int r = 0; r < 4; ++r) {
        int m = m0 + (wm * 4 + i) * 16 + cq * 4 + r;
        int b = m >> 10, t = m & 1023;
        size_t addr = (((size_t)(dir * 16 + swg) * 1024 + t) * 2048) + (q * 16 + b) * 32 + jj;
        xz[addr] = __float2bfloat16(acc[i][j][r] + bv);
      }
    }
}

// ---------------- persistent bidirectional recurrence ----------------
// 32 blocks: dir = blockIdx&1, slice = blockIdx>>1 (16 slices/dir, 32 u-cols).
// LDS: uh 128KB | hbuf 16x(512+8) bf16 = 16640B | zbuf 16x128 f32 = 8KB |
//      xbuf 2048 bf16 = 4KB  -> 160000 B total.
__global__ __launch_bounds__(256) void lstm_rec_k(const __hip_bfloat16* __restrict__ Ut,  // [2][2048][512]
                                                  const __hip_bfloat16* __restrict__ xz,  // [dir][swg][t][2048]
                                                  __hip_bfloat16* __restrict__ ynext,     // [16][1024][1024]
                                                  float* __restrict__ outf,               // last layer or null
                                                  int* __restrict__ arrive) {             // [2][16 slots x 16 ints]
  extern __shared__ char smem[];
  uint4* uh = (uint4*)smem;                          // 8192 x 16B
  __hip_bfloat16* hbuf = (__hip_bfloat16*)(smem + 131072);  // [16][520]
  float* zbuf = (float*)(smem + 147712);             // [16][128]
  __hip_bfloat16* xbuf = (__hip_bfloat16*)(smem + 155904);  // [2048]
  int dir = blockIdx.x & 1;
  int swg = blockIdx.x >> 1;
  int u0 = swg * 32;
  int tid = threadIdx.x, lane = tid & 63, wv = tid >> 6;
  int quad = lane >> 4, l15 = lane & 15;
  const __hip_bfloat16* Ud = Ut + (size_t)dir * 2048 * 512;

  // fill LDS with Uh slice, pre-fragmented (same as R1)
#pragma unroll 4
  for (int i = 0; i < 32; ++i) {
    int slot = i * 256 + tid;
    int ls = slot & 63, kc = (slot >> 6) & 15, nt = slot >> 10;
    int n_g = (nt >> 1) * 512 + u0 + (nt & 1) * 16 + (ls & 15);
    int k = kc * 32 + (ls >> 4) * 8;
    uh[slot] = *(const uint4*)(Ud + (size_t)n_g * 512 + k);
  }
  __syncthreads();

  int nt0 = wv * 2, nt1 = wv * 2 + 1;
  int pb = tid >> 4, pj = (tid & 15) * 2;
  float c0 = 0.f, c1 = 0.f;
  int* slots = arrive + dir * 256;   // 16 slots, 64B apart

  int t0 = dir ? 1023 : 0;
  const uint4* xp0 = (const uint4*)(xz + ((size_t)(dir * 16 + swg) * 1024 + t0) * 2048) + tid;
  uint4 xcur = *xp0;

  for (int s = 0; s < 1024; ++s) {
    int t = dir ? (1023 - s) : s;
    // prefetch next step's xz (flag-independent; overlaps the poll)
    uint4 xnxt;
    if (s < 1023) {
      int tn = dir ? (1022 - s) : (s + 1);
      xnxt = *((const uint4*)(xz + ((size_t)(dir * 16 + swg) * 1024 + tn) * 2048) + tid);
    }
    f32x4 z0 = {}, z1 = {};
    if (s > 0) {
      int tprev = dir ? (t + 1) : (t - 1);
      if (tid < 16) {
        while (__hip_atomic_load(slots + tid * 16, __ATOMIC_RELAXED, __HIP_MEMORY_SCOPE_AGENT) < s) { }
      }
      __syncthreads();
      // cooperative coalesced h -> LDS (agent-scope 8B loads bypass stale caches)
#pragma unroll
      for (int i = 0; i < 4; ++i) {
        int v = i * 2048 + tid * 8;
        int b = v >> 9, col = v & 511;
        const unsigned long long* gp =
            (const unsigned long long*)(ynext + ((size_t)b * 1024 + tprev) * 1024 + dir * 512 + col);
        unsigned long long v0 = __hip_atomic_load(gp, __ATOMIC_RELAXED, __HIP_MEMORY_SCOPE_AGENT);
        unsigned long long v1 = __hip_atomic_load(gp + 1, __ATOMIC_RELAXED, __HIP_MEMORY_SCOPE_AGENT);
        unsigned long long* lp = (unsigned long long*)(hbuf + b * 520 + col);
        lp[0] = v0; lp[1] = v1;
      }
      __syncthreads();
      // A-frags from LDS (b128, 2-way bank alias = free) + MFMA
#pragma unroll
      for (int kc = 0; kc < 16; ++kc) {
        short8 afrag = *(const short8*)(hbuf + l15 * 520 + kc * 32 + quad * 8);
        z0 = __builtin_amdgcn_mfma_f32_16x16x32_bf16(afrag, as_short8(uh[(nt0 * 16 + kc) * 64 + lane]), z0, 0, 0, 0);
        z1 = __builtin_amdgcn_mfma_f32_16x16x32_bf16(afrag, as_short8(uh[(nt1 * 16 + kc) * 64 + lane]), z1, 0, 0, 0);
      }
    }
    // publish z to zbuf; stage xz chunk to xbuf
#pragma unroll
    for (int r = 0; r < 4; ++r) {
      int m = quad * 4 + r;
      zbuf[m * 128 + nt0 * 16 + l15] = z0[r];
      zbuf[m * 128 + nt1 * 16 + l15] = z1[r];
    }
    *(uint4*)(xbuf + tid * 8) = xcur;
    __syncthreads();
    // gates: i,f,g,o = sigmoid; c = f*c + i*g; h = o*sigmoid(c)
    const float* zb = zbuf + pb * 128;
    uint32_t xi = *(const uint32_t*)(xbuf + (0 * 16 + pb) * 32 + pj);
    uint32_t xf = *(const uint32_t*)(xbuf + (1 * 16 + pb) * 32 + pj);
    uint32_t xg = *(const uint32_t*)(xbuf + (2 * 16 + pb) * 32 + pj);
    uint32_t xo = *(const uint32_t*)(xbuf + (3 * 16 + pb) * 32 + pj);
    float i0 = sigf(zb[pj] + bflo(xi)),      i1 = sigf(zb[pj + 1] + bfhi(xi));
    float f0 = sigf(zb[32 + pj] + bflo(xf)), f1 = sigf(zb[32 + pj + 1] + bfhi(xf));
    float g0 = sigf(zb[64 + pj] + bflo(xg)), g1 = sigf(zb[64 + pj + 1] + bfhi(xg));
    float o0 = sigf(zb[96 + pj] + bflo(xo)), o1 = sigf(zb[96 + pj + 1] + bfhi(xo));
    c0 = f0 * c0 + i0 * g0;
    c1 = f1 * c1 + i1 * g1;
    float h0 = o0 * sigf(c0);
    float h1 = o1 * sigf(c1);
    size_t oidx = ((size_t)pb * 1024 + t) * 1024 + dir * 512 + u0 + pj;
    uint32_t hp = f2bfbits(h0) | (f2bfbits(h1) << 16);
    __hip_atomic_store((uint32_t*)(ynext + oidx), hp, __ATOMIC_RELAXED, __HIP_MEMORY_SCOPE_AGENT);
    if (outf) { outf[oidx] = h0; outf[oidx + 1] = h1; }
    __syncthreads();   // drains vmcnt: h stores globally visible (write-through)
    if (tid == 0)
      __hip_atomic_store(slots + swg * 16, s + 1, __ATOMIC_RELEASE, __HIP_MEMORY_SCOPE_AGENT);
    xcur = xnxt;
  }
}

// ---------------------------------------------------------------------------
extern "C" void kernel_launch(void* const* d_in, const int* in_sizes, int n_in,
                              void* d_out, int out_size, void* d_ws, size_t ws_size,
                              hipStream_t stream) {
  const float* x  = (const float*)d_in[0];   // [16][1024][1024]
  const float* W  = (const float*)d_in[1];   // [5][2][1024][2048]
  const float* Uh = (const float*)d_in[2];   // [5][2][512][2048]
  const float* b  = (const float*)d_in[3];   // [5][2][2048]

  char* ws = (char*)d_ws;
  size_t off = 0;
  __hip_bfloat16* yA = (__hip_bfloat16*)(ws + off); off += (size_t)16 * 1024 * 1024 * 2;
  __hip_bfloat16* yB = (__hip_bfloat16*)(ws + off); off += (size_t)16 * 1024 * 1024 * 2;
  __hip_bfloat16* xz = (__hip_bfloat16*)(ws + off); off += (size_t)2 * 16 * 1024 * 2048 * 2;
  __hip_bfloat16* Wt = (__hip_bfloat16*)(ws + off); off += (size_t)2 * 2048 * 1024 * 2;
  __hip_bfloat16* Ut = (__hip_bfloat16*)(ws + off); off += (size_t)2 * 2048 * 512 * 2;
  int* flags = (int*)(ws + off); off += (size_t)5 * 512 * 4;   // per layer: 2 dirs x 16 slots x 64B

  hipMemsetAsync(flags, 0, 5 * 512 * sizeof(int), stream);
  f32_to_bf16_k<<<dim3(16384), dim3(256), 0, stream>>>(x, yA, 4194304);
  hipFuncSetAttribute(reinterpret_cast<const void*>(lstm_rec_k),
                      hipFuncAttributeMaxDynamicSharedMemorySize, 160000);
  for (int l = 0; l < 5; ++l) {
    transpose_bf16_k<<<dim3(16, 32, 2), dim3(256), 0, stream>>>(W + (size_t)l * 2 * 1024 * 2048, Wt, 1024);
    transpose_bf16_k<<<dim3(8, 32, 2),  dim3(256), 0, stream>>>(Uh + (size_t)l * 2 * 512 * 2048, Ut, 512);
    __hip_bfloat16* ycur = (l & 1) ? yB : yA;
    __hip_bfloat16* ynxt = (l & 1) ? yA : yB;
    gemm_xz_k<<<dim3(128, 32), dim3(256), 0, stream>>>(ycur, Wt, b + (size_t)l * 2 * 2048, xz);
    lstm_rec_k<<<dim3(32), dim3(256), 160000, stream>>>(
        Ut, xz, ynxt, (l == 4) ? (float*)d_out : nullptr, flags + l * 512);
  }
}